// Round 10
// baseline (588.253 us; speedup 1.0000x reference)
//
#include <hip/hip_runtime.h>
#include <hip/hip_fp16.h>
#include <math.h>

namespace {
constexpr int kB = 16;
constexpr int kV = 500000;
constexpr int kF = 1000000;
constexpr float kEps = 1e-6f;
constexpr int kNB = (kV + 255) / 256;     // 1954
constexpr int kNSweep = 8;                // fill sweeps; v>>16 in 0..7 (kV<2^19)

// vtx16: [V] records of 32 uints (24 used = 48 fp16 comps, pad to 128 B line)
// fn16 : [F] records of 32 uints (24 used = 48 fp16 comps, pad to 128 B line)
constexpr size_t kVtx16Uints = (size_t)kV * 32;    // 64 MB
constexpr size_t kFn16Uints  = (size_t)kF * 32;    // 128 MB
constexpr size_t kIntBytes   = ((size_t)kV + (kV + 1) + kNB + 3 * (size_t)kF) * 4;
constexpr size_t kWs16 = (kVtx16Uints + kFn16Uints) * 4 + kIntBytes;  // ~208 MB
constexpr size_t kWsC  = kIntBytes;                                   // ~16 MB
}

// a*b - c*d unfused: degenerate faces cancel EXACTLY (matches numpy; the
// fp16-rounded coords of duplicate indices are identical, so e2 = -e1 and
// both products round identically). FMA contraction would leave ulp noise
// that normalization amplifies to O(1).
__device__ __forceinline__ float cross_comp(float a, float b, float c, float d) {
    return __fsub_rn(__fmul_rn(a, b), __fmul_rn(c, d));
}

__device__ __forceinline__ unsigned pack2(float a, float b) {
    __half2 h = __halves2half2(__float2half_rn(a), __float2half_rn(b));
    return __builtin_bit_cast(unsigned, h);
}
__device__ __forceinline__ float2 unpack2(unsigned u) {
    return __half22float2(__builtin_bit_cast(__half2, u));
}

// Stage 64 records/wave (8 KB) in LDS, then write out so every store
// instruction covers 8 FULL 128 B lines (1 KB contiguous per wave per
// iteration) -> no read-for-ownership / write-allocate fetches.
// lds layout: [wave][record][slot], slot rotated by record for bank spread.
__device__ __forceinline__ void staged_record_write(
    uint4 lds[4][64][8], const uint4 q[8], uint4* __restrict__ dstBase,
    size_t baseRec, int maxRec, int wave, int lane)
{
#pragma unroll
    for (int k = 0; k < 8; ++k)
        lds[wave][lane][(k + lane) & 7] = q[k];
    __syncthreads();
    uint4* dst = dstBase + baseRec * 8;
#pragma unroll
    for (int k = 0; k < 8; ++k) {
        int g = k * 64 + lane;          // uint4 index within wave's 8 KB
        int r = g >> 3, w = g & 7;
        if (baseRec + (size_t)r < (size_t)maxRec)
            dst[g] = lds[wave][r][(w + r) & 7];
    }
}

// ---------- CSR build (bitwise-deterministic end state) ----------

__global__ __launch_bounds__(256) void zero_count_kernel(int* __restrict__ count) {
    int i = blockIdx.x * 256 + threadIdx.x;
    if (i < kV) count[i] = 0;
}

__global__ __launch_bounds__(256) void count_kernel(
    const int* __restrict__ faces, int* __restrict__ count)
{
    int i = blockIdx.x * 256 + threadIdx.x;
    if (i >= 3 * kF) return;
    atomicAdd(&count[faces[i]], 1);
}

__device__ __forceinline__ int block_incl_scan256(int x, int* lds) {
    int lane = threadIdx.x & 63;
    int wave = threadIdx.x >> 6;
    for (int d = 1; d < 64; d <<= 1) {
        int y = __shfl_up(x, d, 64);
        if (lane >= d) x += y;
    }
    if (lane == 63) lds[wave] = x;
    __syncthreads();
    int add = 0;
    for (int w = 0; w < wave; ++w) add += lds[w];
    __syncthreads();
    return x + add;
}

__global__ __launch_bounds__(256) void scan_block_kernel(
    const int* __restrict__ count, int* __restrict__ offs,
    int* __restrict__ blockSums)
{
    __shared__ int lds[4];
    int i = blockIdx.x * 256 + threadIdx.x;
    int x = (i < kV) ? count[i] : 0;
    int incl = block_incl_scan256(x, lds);
    if (i < kV) offs[i] = incl - x;
    if (threadIdx.x == 255) blockSums[blockIdx.x] = incl;
}

__global__ __launch_bounds__(256) void scan_sums_kernel(int* __restrict__ blockSums) {
    __shared__ int lds[4];
    __shared__ int carry;
    if (threadIdx.x == 0) carry = 0;
    __syncthreads();
    for (int base = 0; base < kNB; base += 256) {
        int i = base + threadIdx.x;
        int x = (i < kNB) ? blockSums[i] : 0;
        int incl = block_incl_scan256(x, lds);
        int c = carry;
        __syncthreads();
        if (i < kNB) blockSums[i] = incl - x + c;
        if (threadIdx.x == 255) carry = c + incl;
        __syncthreads();
    }
}

__global__ __launch_bounds__(256) void add_offsets_kernel(
    int* __restrict__ offs, const int* __restrict__ blockSums)
{
    int i = blockIdx.x * 256 + threadIdx.x;
    if (i < kV) offs[i] += blockSums[i >> 8];
    if (i == kV) offs[kV] = 3 * kF;
}

// Swept fill: sweep s handles vertices with (v>>16)&7 == s (a contiguous
// 64K-vertex range -> ~1.5 MB adj slice + 256 KB count slice, L2-resident).
// Lines in the slice collect ALL their slot-writes within one sweep ->
// writeback ~12 MB total instead of 3M x 64 B sectors. Separate launches
// per sweep provide the global barrier that bounds each line's fill window.
__global__ __launch_bounds__(256) void fill_adj_sweep_kernel(
    const int* __restrict__ faces, const int* __restrict__ offs,
    int* __restrict__ count, int* __restrict__ adj, int sweep)
{
    int i = blockIdx.x * 256 + threadIdx.x;
    if (i >= 3 * kF) return;
    int v = faces[i];
    if (((v >> 16) & 7) != sweep) return;
    int f = i / 3;
    int old = atomicSub(&count[v], 1);
    adj[offs[v] + old - 1] = f;
}

// canonicalize slot order -> bitwise-deterministic adj -> deterministic fp sums
__global__ __launch_bounds__(256) void sort_rows_kernel(
    const int* __restrict__ offs, int* __restrict__ adj)
{
    int v = blockIdx.x * 256 + threadIdx.x;
    if (v >= kV) return;
    int s = offs[v], e = offs[v + 1];
    for (int i = s + 1; i < e; ++i) {
        int key = adj[i];
        int j = i - 1;
        while (j >= s && adj[j] > key) { adj[j + 1] = adj[j]; --j; }
        adj[j + 1] = key;
    }
}

// ---------- fp16-record path ----------

// verts [B][V][3] -> vtx16 [V][32u]; staged full-line writes (no RFO).
__global__ __launch_bounds__(256) void transpose_kernel16(
    const float* __restrict__ verts, unsigned* __restrict__ vtx16)
{
    __shared__ uint4 lds[4][64][8];
    int tid = threadIdx.x;
    int wave = tid >> 6, lane = tid & 63;
    int v = blockIdx.x * 256 + tid;
    bool valid = v < kV;

    float o[48];
#pragma unroll
    for (int i = 0; i < 48; ++i) o[i] = 0.f;
    if (valid) {
#pragma unroll
        for (int b = 0; b < kB; ++b) {
            const float* p = verts + ((size_t)b * kV + v) * 3;
            o[3 * b + 0] = p[0];
            o[3 * b + 1] = p[1];
            o[3 * b + 2] = p[2];
        }
    }
    uint4 q[8];
#pragma unroll
    for (int k = 0; k < 6; ++k)
        q[k] = make_uint4(pack2(o[8 * k + 0], o[8 * k + 1]),
                          pack2(o[8 * k + 2], o[8 * k + 3]),
                          pack2(o[8 * k + 4], o[8 * k + 5]),
                          pack2(o[8 * k + 6], o[8 * k + 7]));
    q[6] = make_uint4(0u, 0u, 0u, 0u);
    q[7] = make_uint4(0u, 0u, 0u, 0u);

    size_t baseRec = (size_t)blockIdx.x * 256 + wave * 64;
    staged_record_write(lds, q, reinterpret_cast<uint4*>(vtx16),
                        baseRec, kV, wave, lane);
}

// Per face: 3 ONE-granule record gathers, 16 fp32 crosses from fp16 coords,
// areas (coalesced full lines, NT), fn16 via staged full-line writes.
__global__ __launch_bounds__(256) void face_kernel16(
    const unsigned* __restrict__ vtx16, const int* __restrict__ faces,
    unsigned* __restrict__ fn16, float* __restrict__ areas)
{
    __shared__ uint4 lds[4][64][8];
    int tid = threadIdx.x;
    int wave = tid >> 6, lane = tid & 63;
    int f = blockIdx.x * 256 + tid;
    bool valid = f < kF;

    float o[48];
#pragma unroll
    for (int i = 0; i < 48; ++i) o[i] = 0.f;

    if (valid) {
        int i0 = faces[3 * f + 0];
        int i1 = faces[3 * f + 1];
        int i2 = faces[3 * f + 2];
        const uint4* r0 = reinterpret_cast<const uint4*>(vtx16 + (size_t)i0 * 32);
        const uint4* r1 = reinterpret_cast<const uint4*>(vtx16 + (size_t)i1 * 32);
        const uint4* r2 = reinterpret_cast<const uint4*>(vtx16 + (size_t)i2 * 32);
#pragma unroll
        for (int g = 0; g < 2; ++g) {      // 8 batches per group (VGPR control)
            float A[24], B[24], C[24];
#pragma unroll
            for (int k = 0; k < 3; ++k) {
                uint4 ua = r0[3 * g + k], ub = r1[3 * g + k], uc = r2[3 * g + k];
                float2 t;
                t = unpack2(ua.x); A[8 * k + 0] = t.x; A[8 * k + 1] = t.y;
                t = unpack2(ua.y); A[8 * k + 2] = t.x; A[8 * k + 3] = t.y;
                t = unpack2(ua.z); A[8 * k + 4] = t.x; A[8 * k + 5] = t.y;
                t = unpack2(ua.w); A[8 * k + 6] = t.x; A[8 * k + 7] = t.y;
                t = unpack2(ub.x); B[8 * k + 0] = t.x; B[8 * k + 1] = t.y;
                t = unpack2(ub.y); B[8 * k + 2] = t.x; B[8 * k + 3] = t.y;
                t = unpack2(ub.z); B[8 * k + 4] = t.x; B[8 * k + 5] = t.y;
                t = unpack2(ub.w); B[8 * k + 6] = t.x; B[8 * k + 7] = t.y;
                t = unpack2(uc.x); C[8 * k + 0] = t.x; C[8 * k + 1] = t.y;
                t = unpack2(uc.y); C[8 * k + 2] = t.x; C[8 * k + 3] = t.y;
                t = unpack2(uc.z); C[8 * k + 4] = t.x; C[8 * k + 5] = t.y;
                t = unpack2(uc.w); C[8 * k + 6] = t.x; C[8 * k + 7] = t.y;
            }
#pragma unroll
            for (int bb = 0; bb < 8; ++bb) {
                float x0 = A[3 * bb], y0 = A[3 * bb + 1], z0 = A[3 * bb + 2];
                float x1 = B[3 * bb], y1 = B[3 * bb + 1], z1 = B[3 * bb + 2];
                float x2 = C[3 * bb], y2 = C[3 * bb + 1], z2 = C[3 * bb + 2];
                float e1x = x1 - x0, e1y = y1 - y0, e1z = z1 - z0;
                float e2x = x2 - x1, e2y = y2 - y1, e2z = z2 - z1;
                float nx = cross_comp(e1y, e2z, e1z, e2y);
                float ny = cross_comp(e1z, e2x, e1x, e2z);
                float nz = cross_comp(e1x, e2y, e1y, e2x);
                int bi = 8 * g + bb;
                o[3 * bi + 0] = nx;
                o[3 * bi + 1] = ny;
                o[3 * bi + 2] = nz;
                // wave writes 256 B contiguous per bi -> full lines, no RFO
                __builtin_nontemporal_store(
                    0.5f * sqrtf(nx * nx + ny * ny + nz * nz),
                    &areas[(size_t)bi * kF + f]);
            }
        }
    }

    uint4 q[8];
#pragma unroll
    for (int k = 0; k < 6; ++k)
        q[k] = make_uint4(pack2(o[8 * k + 0], o[8 * k + 1]),
                          pack2(o[8 * k + 2], o[8 * k + 3]),
                          pack2(o[8 * k + 4], o[8 * k + 5]),
                          pack2(o[8 * k + 6], o[8 * k + 7]));
    q[6] = make_uint4(0u, 0u, 0u, 0u);
    q[7] = make_uint4(0u, 0u, 0u, 0u);

    size_t baseRec = (size_t)blockIdx.x * 256 + wave * 64;
    staged_record_write(lds, q, reinterpret_cast<uint4*>(fn16),
                        baseRec, kF, wave, lane);
}

// Per vertex: walk sorted CSR, ONE-granule fn16 gathers (all 16 batches),
// fp32 accumulate, normalize, NT store.
__global__ __launch_bounds__(256) void vertex_kernel16(
    const unsigned* __restrict__ fn16, const int* __restrict__ offs,
    const int* __restrict__ adj, float* __restrict__ out)
{
    int v = blockIdx.x * 256 + threadIdx.x;
    if (v >= kV) return;
    int s = offs[v], e = offs[v + 1];

    float acc[48];
#pragma unroll
    for (int i = 0; i < 48; ++i) acc[i] = 0.f;

    for (int j = s; j < e; ++j) {
        const uint4* q = reinterpret_cast<const uint4*>(fn16 + (size_t)adj[j] * 32);
        uint4 w[6];
#pragma unroll
        for (int k = 0; k < 6; ++k) w[k] = q[k];
#pragma unroll
        for (int k = 0; k < 6; ++k) {
            float2 t0 = unpack2(w[k].x), t1 = unpack2(w[k].y);
            float2 t2 = unpack2(w[k].z), t3 = unpack2(w[k].w);
            acc[8 * k + 0] += t0.x; acc[8 * k + 1] += t0.y;
            acc[8 * k + 2] += t1.x; acc[8 * k + 3] += t1.y;
            acc[8 * k + 4] += t2.x; acc[8 * k + 5] += t2.y;
            acc[8 * k + 6] += t3.x; acc[8 * k + 7] += t3.y;
        }
    }

#pragma unroll
    for (int bi = 0; bi < kB; ++bi) {
        float x = acc[3 * bi], y = acc[3 * bi + 1], z = acc[3 * bi + 2];
        float n = sqrtf(x * x + y * y + z * z);
        float inv = 1.0f / fmaxf(n, kEps);
        size_t o = ((size_t)bi * kV + v) * 3;
        __builtin_nontemporal_store(x * inv, &out[o + 0]);
        __builtin_nontemporal_store(y * inv, &out[o + 1]);
        __builtin_nontemporal_store(z * inv, &out[o + 2]);
    }
}

// ---------- R3 fallback (ws >= 16 MB) ----------

__global__ __launch_bounds__(256) void fill_adj_kernel(
    const int* __restrict__ faces, const int* __restrict__ offs,
    int* __restrict__ count, int* __restrict__ adj)
{
    int i = blockIdx.x * 256 + threadIdx.x;
    if (i >= 3 * kF) return;
    int v = faces[i];
    int f = i / 3;
    int old = atomicSub(&count[v], 1);
    adj[offs[v] + old - 1] = f;
}

__global__ __launch_bounds__(256) void area_kernel_orig(
    const float* __restrict__ verts, const int* __restrict__ faces,
    float* __restrict__ areas)
{
    int f = blockIdx.x * 256 + threadIdx.x;
    if (f >= kF) return;
    int i0 = faces[3 * f + 0];
    int i1 = faces[3 * f + 1];
    int i2 = faces[3 * f + 2];
    size_t o0 = 3 * (size_t)i0, o1 = 3 * (size_t)i1, o2 = 3 * (size_t)i2;
#pragma unroll
    for (int b = 0; b < kB; ++b) {
        const float* vb = verts + (size_t)b * kV * 3;
        float x0 = vb[o0], y0 = vb[o0 + 1], z0 = vb[o0 + 2];
        float x1 = vb[o1], y1 = vb[o1 + 1], z1 = vb[o1 + 2];
        float x2 = vb[o2], y2 = vb[o2 + 1], z2 = vb[o2 + 2];
        float e1x = x1 - x0, e1y = y1 - y0, e1z = z1 - z0;
        float e2x = x2 - x1, e2y = y2 - y1, e2z = z2 - z1;
        float nx = cross_comp(e1y, e2z, e1z, e2y);
        float ny = cross_comp(e1z, e2x, e1x, e2z);
        float nz = cross_comp(e1x, e2y, e1y, e2x);
        areas[(size_t)b * kF + f] = 0.5f * sqrtf(nx * nx + ny * ny + nz * nz);
    }
}

__global__ __launch_bounds__(256) void gather_normalize_orig(
    const float* __restrict__ verts, const int* __restrict__ faces,
    const int* __restrict__ offs, const int* __restrict__ adj,
    float* __restrict__ out)
{
    int v = blockIdx.x * 256 + threadIdx.x;
    if (v >= kV) return;
    int s = offs[v], e = offs[v + 1];
    float ax[kB], ay[kB], az[kB];
#pragma unroll
    for (int b = 0; b < kB; ++b) { ax[b] = 0.f; ay[b] = 0.f; az[b] = 0.f; }
    for (int j = s; j < e; ++j) {
        int f = adj[j];
        int i0 = faces[3 * f + 0];
        int i1 = faces[3 * f + 1];
        int i2 = faces[3 * f + 2];
        size_t o0 = 3 * (size_t)i0, o1 = 3 * (size_t)i1, o2 = 3 * (size_t)i2;
#pragma unroll
        for (int b = 0; b < kB; ++b) {
            const float* vb = verts + (size_t)b * kV * 3;
            float x0 = vb[o0], y0 = vb[o0 + 1], z0 = vb[o0 + 2];
            float x1 = vb[o1], y1 = vb[o1 + 1], z1 = vb[o1 + 2];
            float x2 = vb[o2], y2 = vb[o2 + 1], z2 = vb[o2 + 2];
            float e1x = x1 - x0, e1y = y1 - y0, e1z = z1 - z0;
            float e2x = x2 - x1, e2y = y2 - y1, e2z = z2 - z1;
            ax[b] += cross_comp(e1y, e2z, e1z, e2y);
            ay[b] += cross_comp(e1z, e2x, e1x, e2z);
            az[b] += cross_comp(e1x, e2y, e1y, e2x);
        }
    }
#pragma unroll
    for (int b = 0; b < kB; ++b) {
        float n = sqrtf(ax[b] * ax[b] + ay[b] * ay[b] + az[b] * az[b]);
        float inv = 1.0f / fmaxf(n, kEps);
        size_t o = ((size_t)b * kV + v) * 3;
        out[o + 0] = ax[b] * inv;
        out[o + 1] = ay[b] * inv;
        out[o + 2] = az[b] * inv;
    }
}

// ---------- R1 fallback ----------

__global__ __launch_bounds__(256) void face_normals_atomic_kernel(
    const float* __restrict__ verts, const int* __restrict__ faces,
    float* __restrict__ vnorm, float* __restrict__ areas)
{
    long long tid = (long long)blockIdx.x * blockDim.x + threadIdx.x;
    if (tid >= (long long)kB * kF) return;
    int f = (int)(tid % kF);
    int b = (int)(tid / kF);
    int i0 = faces[3 * f + 0], i1 = faces[3 * f + 1], i2 = faces[3 * f + 2];
    const float* vb = verts + (size_t)b * kV * 3;
    size_t o0 = 3 * (size_t)i0, o1 = 3 * (size_t)i1, o2 = 3 * (size_t)i2;
    float x0 = vb[o0], y0 = vb[o0 + 1], z0 = vb[o0 + 2];
    float x1 = vb[o1], y1 = vb[o1 + 1], z1 = vb[o1 + 2];
    float x2 = vb[o2], y2 = vb[o2 + 1], z2 = vb[o2 + 2];
    float e1x = x1 - x0, e1y = y1 - y0, e1z = z1 - z0;
    float e2x = x2 - x1, e2y = y2 - y1, e2z = z2 - z1;
    float nx = cross_comp(e1y, e2z, e1z, e2y);
    float ny = cross_comp(e1z, e2x, e1x, e2z);
    float nz = cross_comp(e1x, e2y, e1y, e2x);
    float* vn = vnorm + (size_t)b * kV * 3;
    unsafeAtomicAdd(&vn[o0 + 0], nx); unsafeAtomicAdd(&vn[o0 + 1], ny); unsafeAtomicAdd(&vn[o0 + 2], nz);
    unsafeAtomicAdd(&vn[o1 + 0], nx); unsafeAtomicAdd(&vn[o1 + 1], ny); unsafeAtomicAdd(&vn[o1 + 2], nz);
    unsafeAtomicAdd(&vn[o2 + 0], nx); unsafeAtomicAdd(&vn[o2 + 1], ny); unsafeAtomicAdd(&vn[o2 + 2], nz);
    areas[(size_t)b * kF + f] = 0.5f * sqrtf(nx * nx + ny * ny + nz * nz);
}

__global__ __launch_bounds__(256) void normalize_inplace_kernel(float* __restrict__ vnorm) {
    long long tid = (long long)blockIdx.x * blockDim.x + threadIdx.x;
    if (tid >= (long long)kB * kV) return;
    size_t o = 3 * (size_t)tid;
    float x = vnorm[o], y = vnorm[o + 1], z = vnorm[o + 2];
    float n = sqrtf(x * x + y * y + z * z);
    float inv = 1.0f / fmaxf(n, kEps);
    vnorm[o] = x * inv; vnorm[o + 1] = y * inv; vnorm[o + 2] = z * inv;
}

// ---------- launch ----------

static void build_csr_swept(const int* faces, int* count, int* offs,
                            int* blockSums, int* adj, hipStream_t stream) {
    int gInc = (3 * kF + 255) / 256;
    zero_count_kernel<<<kNB, 256, 0, stream>>>(count);
    count_kernel<<<gInc, 256, 0, stream>>>(faces, count);
    scan_block_kernel<<<kNB, 256, 0, stream>>>(count, offs, blockSums);
    scan_sums_kernel<<<1, 256, 0, stream>>>(blockSums);
    add_offsets_kernel<<<(kV + 1 + 255) / 256, 256, 0, stream>>>(offs, blockSums);
    for (int s = 0; s < kNSweep; ++s)
        fill_adj_sweep_kernel<<<gInc, 256, 0, stream>>>(faces, offs, count, adj, s);
    sort_rows_kernel<<<kNB, 256, 0, stream>>>(offs, adj);
}

static void build_csr(const int* faces, int* count, int* offs, int* blockSums,
                      int* adj, hipStream_t stream) {
    int gInc = (3 * kF + 255) / 256;
    zero_count_kernel<<<kNB, 256, 0, stream>>>(count);
    count_kernel<<<gInc, 256, 0, stream>>>(faces, count);
    scan_block_kernel<<<kNB, 256, 0, stream>>>(count, offs, blockSums);
    scan_sums_kernel<<<1, 256, 0, stream>>>(blockSums);
    add_offsets_kernel<<<(kV + 1 + 255) / 256, 256, 0, stream>>>(offs, blockSums);
    fill_adj_kernel<<<gInc, 256, 0, stream>>>(faces, offs, count, adj);
    sort_rows_kernel<<<kNB, 256, 0, stream>>>(offs, adj);
}

extern "C" void kernel_launch(void* const* d_in, const int* in_sizes, int n_in,
                              void* d_out, int out_size, void* d_ws, size_t ws_size,
                              hipStream_t stream) {
    const float* verts = (const float*)d_in[0];
    const int*   faces = (const int*)d_in[1];

    float* out   = (float*)d_out;
    float* vecs  = out;                               // B*V*3
    float* areas = out + (size_t)kB * kV * 3;         // B*F

    int gF = (kF + 255) / 256;

    if (ws_size >= kWs16) {
        unsigned* vtx16 = (unsigned*)d_ws;                    // 64 MB
        unsigned* fn16  = vtx16 + kVtx16Uints;                // 128 MB
        int* count     = (int*)(fn16 + kFn16Uints);
        int* offs      = count + kV;
        int* blockSums = offs + (kV + 1);
        int* adj       = blockSums + kNB;

        build_csr_swept(faces, count, offs, blockSums, adj, stream);
        transpose_kernel16<<<kNB, 256, 0, stream>>>(verts, vtx16);
        face_kernel16<<<gF, 256, 0, stream>>>(vtx16, faces, fn16, areas);
        vertex_kernel16<<<kNB, 256, 0, stream>>>(fn16, offs, adj, vecs);
    } else if (ws_size >= kWsC) {
        int* count     = (int*)d_ws;
        int* offs      = count + kV;
        int* blockSums = offs + (kV + 1);
        int* adj       = blockSums + kNB;

        build_csr(faces, count, offs, blockSums, adj, stream);
        area_kernel_orig<<<gF, 256, 0, stream>>>(verts, faces, areas);
        gather_normalize_orig<<<kNB, 256, 0, stream>>>(verts, faces, offs, adj, vecs);
    } else {
        (void)hipMemsetAsync(vecs, 0, (size_t)kB * kV * 3 * sizeof(float), stream);
        long long nf = (long long)kB * kF;
        face_normals_atomic_kernel<<<(int)((nf + 255) / 256), 256, 0, stream>>>(verts, faces, vecs, areas);
        long long nv = (long long)kB * kV;
        normalize_inplace_kernel<<<(int)((nv + 255) / 256), 256, 0, stream>>>(vecs);
    }
}